// Round 2
// 291.119 us; speedup vs baseline: 1.3011x; 1.3011x over previous
//
#include <hip/hip_runtime.h>
#include <math.h>

#define B 8
#define S 2048
#define DM 1024
#define DK 64
#define M_ROWS (B*S)

typedef short s8v __attribute__((ext_vector_type(8)));     // 8 bf16 (4 VGPR)
typedef float f4v __attribute__((ext_vector_type(4)));     // 4 fp32
typedef unsigned short us4 __attribute__((ext_vector_type(4)));

__device__ __forceinline__ unsigned short f2bf(float f) {
    union { float f; unsigned u; } v; v.f = f;
    unsigned r = v.u + 0x7fffu + ((v.u >> 16) & 1u);   // RNE
    return (unsigned short)(r >> 16);
}
__device__ __forceinline__ s8v ld8(const unsigned short* p) {
    return *(const s8v*)p;
}
__device__ __forceinline__ f4v mf16(s8v a, s8v b, f4v c) {
    return __builtin_amdgcn_mfma_f32_16x16x32_bf16(a, b, c, 0, 0, 0);
}
// async global->LDS, 16B per lane. LDS dest = wave base + lane*16 (pass per-lane
// ptr so either HW addressing interpretation lands each lane's data correctly).
__device__ __forceinline__ void gload16(const unsigned short* g, unsigned short* l) {
    __builtin_amdgcn_global_load_lds(
        (const __attribute__((address_space(1))) void*)g,
        (__attribute__((address_space(3))) void*)l, 16, 0, 0);
}
// lgkm-only barrier: LDS writes visible, but vmcnt (async V loads) stays in flight
__device__ __forceinline__ void bar_lgkm() {
    asm volatile("s_waitcnt lgkmcnt(0)" ::: "memory");
    __builtin_amdgcn_s_barrier();
}

// ---------------- cast x (fp32 -> bf16) ----------------
__global__ __launch_bounds__(256) void cast_x(const float* __restrict__ x,
                                              unsigned short* __restrict__ xb) {
    size_t i = ((size_t)blockIdx.x * 256 + threadIdx.x) * 4;
    float4 v = *(const float4*)(x + i);
    us4 o; o.x = f2bf(v.x); o.y = f2bf(v.y); o.z = f2bf(v.z); o.w = f2bf(v.w);
    *(us4*)(xb + i) = o;
}

// ---------------- transpose + cast Wv -> Wvt[n][k] bf16 ----------------
__global__ __launch_bounds__(256) void wv_t(const float* __restrict__ Wv,
                                            unsigned short* __restrict__ Wvt) {
    __shared__ float T[32][33];
    int t = threadIdx.x;
    int k0 = blockIdx.y * 32, n0 = blockIdx.x * 32;
    int r = t >> 3, c = (t & 7) * 4;
    float4 v = *(const float4*)(Wv + (size_t)(k0 + r) * DM + n0 + c);
    T[r][c + 0] = v.x; T[r][c + 1] = v.y; T[r][c + 2] = v.z; T[r][c + 3] = v.w;
    __syncthreads();
    us4 o;
    o.x = f2bf(T[c + 0][r]); o.y = f2bf(T[c + 1][r]);
    o.z = f2bf(T[c + 2][r]); o.w = f2bf(T[c + 3][r]);
    *(us4*)(Wvt + (size_t)(n0 + r) * DM + k0 + c) = o;
}

// ---------------- transpose + cast Wq|Wk -> Wqkt[128][1024] bf16 ----------
__global__ __launch_bounds__(256) void wqk_t(const float* __restrict__ Wq,
                                             const float* __restrict__ Wk,
                                             unsigned short* __restrict__ Wqkt) {
    __shared__ float T[32][33];
    int t = threadIdx.x;
    int k0 = blockIdx.y * 32, n0 = blockIdx.x * 32;
    const float* src = (n0 < 64) ? Wq : Wk;
    int nc = (n0 < 64) ? n0 : (n0 - 64);
    int r = t >> 3, c = (t & 7) * 4;
    float4 v = *(const float4*)(src + (size_t)(k0 + r) * DK + nc + c);
    T[r][c + 0] = v.x; T[r][c + 1] = v.y; T[r][c + 2] = v.z; T[r][c + 3] = v.w;
    __syncthreads();
    us4 o;
    o.x = f2bf(T[c + 0][r]); o.y = f2bf(T[c + 1][r]);
    o.z = f2bf(T[c + 2][r]); o.w = f2bf(T[c + 3][r]);
    *(us4*)(Wqkt + (size_t)(n0 + r) * DM + k0 + c) = o;
}

// ---------------- Q/K projection: m97-style, global_load_lds, BK=64 -------
// Tile 64m x 128n. Q output prescaled by 1/sqrt(DK)=0.125.
// LDS linear (gload_lds requirement); XOR-swizzle (chunk ^ row&7) applied on the
// GLOBAL source and on the ds_read side (both-sides, rule #21) -> ~2-way reads.
__global__ __launch_bounds__(256) void qk_mfma(
        const unsigned short* __restrict__ xb,
        const unsigned short* __restrict__ Wqkt,
        const float* __restrict__ bq, const float* __restrict__ bk,
        unsigned short* __restrict__ Q, unsigned short* __restrict__ Ko) {
    __shared__ unsigned short XS[64 * 64];
    __shared__ unsigned short WS[128 * 64];
    int t = threadIdx.x;
    int w = t >> 6, lane = t & 63, l16 = lane & 15, quad = lane >> 4;
    int m0 = blockIdx.x * 64;
    int wm = (w >> 1) * 32, wn = (w & 1) * 64;
    f4v acc[2][4] = {};
    int srow = w * 8 + (lane >> 3);                 // + i*32 per call
    int scol = ((lane & 7) ^ (srow & 7)) * 8;       // inverse-swizzled source chunk
    int soff = w * 512 + lane * 8;                  // + i*2048 (elems)
    for (int k0 = 0; k0 < DM; k0 += 64) {
        __syncthreads();
        #pragma unroll
        for (int i = 0; i < 2; ++i)
            gload16(xb + (size_t)(m0 + i * 32 + srow) * DM + k0 + scol,
                    XS + i * 2048 + soff);
        #pragma unroll
        for (int i = 0; i < 4; ++i)
            gload16(Wqkt + (size_t)(i * 32 + srow) * DM + k0 + scol,
                    WS + i * 2048 + soff);
        __syncthreads();
        #pragma unroll
        for (int ks = 0; ks < 2; ++ks) {
            s8v af[2], bf[4];
            #pragma unroll
            for (int i = 0; i < 2; ++i) {
                int r = wm + i * 16 + l16;
                af[i] = *(const s8v*)&XS[r * 64 + ((ks * 4 + quad) ^ (r & 7)) * 8];
            }
            #pragma unroll
            for (int j = 0; j < 4; ++j) {
                int r = wn + j * 16 + l16;
                bf[j] = *(const s8v*)&WS[r * 64 + ((ks * 4 + quad) ^ (r & 7)) * 8];
            }
            #pragma unroll
            for (int i = 0; i < 2; ++i)
                #pragma unroll
                for (int j = 0; j < 4; ++j)
                    acc[i][j] = mf16(af[i], bf[j], acc[i][j]);
        }
    }
    #pragma unroll
    for (int j = 0; j < 4; ++j) {
        int n = wn + j * 16 + l16;
        float bias = (n < 64) ? bq[n] : bk[n - 64];
        float scale = (n < 64) ? 0.125f : 1.0f;
        unsigned short* dst = (n < 64) ? Q : Ko;
        int nn = n & 63;
        #pragma unroll
        for (int i = 0; i < 2; ++i)
            #pragma unroll
            for (int rr = 0; rr < 4; ++rr) {
                int m = m0 + wm + i * 16 + quad * 4 + rr;
                dst[(size_t)m * DK + nn] = f2bf((acc[i][j][rr] + bias) * scale);
            }
    }
}

// ---------------- V projection: m97-style, global_load_lds, BK=64 ---------
// Tile 128m x 128n, writes Vt[b][n][s] bf16.
__global__ __launch_bounds__(256) void v_proj_mfma(
        const unsigned short* __restrict__ xb,
        const unsigned short* __restrict__ Wvt,
        const float* __restrict__ bv,
        unsigned short* __restrict__ Vt) {
    __shared__ unsigned short XS[128 * 64];
    __shared__ unsigned short WS[128 * 64];
    int t = threadIdx.x;
    int w = t >> 6, lane = t & 63, l16 = lane & 15, quad = lane >> 4;
    int m0 = blockIdx.y * 128, n0 = blockIdx.x * 128;
    int wm = (w >> 1) * 64, wn = (w & 1) * 64;
    f4v acc[4][4] = {};
    int srow = w * 8 + (lane >> 3);
    int scol = ((lane & 7) ^ (srow & 7)) * 8;
    int soff = w * 512 + lane * 8;
    for (int k0 = 0; k0 < DM; k0 += 64) {
        __syncthreads();
        #pragma unroll
        for (int i = 0; i < 4; ++i) {
            gload16(xb  + (size_t)(m0 + i * 32 + srow) * DM + k0 + scol,
                    XS + i * 2048 + soff);
            gload16(Wvt + (size_t)(n0 + i * 32 + srow) * DM + k0 + scol,
                    WS + i * 2048 + soff);
        }
        __syncthreads();
        #pragma unroll
        for (int ks = 0; ks < 2; ++ks) {
            s8v af[4], bf[4];
            #pragma unroll
            for (int i = 0; i < 4; ++i) {
                int r = wm + i * 16 + l16;
                af[i] = *(const s8v*)&XS[r * 64 + ((ks * 4 + quad) ^ (r & 7)) * 8];
            }
            #pragma unroll
            for (int j = 0; j < 4; ++j) {
                int r = wn + j * 16 + l16;
                bf[j] = *(const s8v*)&WS[r * 64 + ((ks * 4 + quad) ^ (r & 7)) * 8];
            }
            #pragma unroll
            for (int i = 0; i < 4; ++i)
                #pragma unroll
                for (int j = 0; j < 4; ++j)
                    acc[i][j] = mf16(af[i], bf[j], acc[i][j]);
        }
    }
    int bb = m0 >> 11;
    #pragma unroll
    for (int j = 0; j < 4; ++j) {
        int n = n0 + wn + j * 16 + l16;
        float bias = bv[n];
        #pragma unroll
        for (int i = 0; i < 4; ++i) {
            int m = m0 + wm + i * 16 + quad * 4;
            int s = m & (S - 1);
            us4 o;
            o.x = f2bf(acc[i][j][0] + bias); o.y = f2bf(acc[i][j][1] + bias);
            o.z = f2bf(acc[i][j][2] + bias); o.w = f2bf(acc[i][j][3] + bias);
            *(us4*)(Vt + ((size_t)bb * DM + n) * S + s) = o;
        }
    }
}

// ---------------- MFMA flash attention v3 ----------------
// Block: q-tile PAIR (y, 15-y) x 128 dm-slice -> uniform 34 j-tiles/block
// (causal balance). V double-buffered via async global_load_lds (pre-swizzled
// source); K prefetched to regs, written to LDS during PV. 2 barriers/j-tile;
// QK->PV barrier is lgkm-only so V loads stay in flight across it.
__global__ __launch_bounds__(256, 2) void attn_mfma(
        const unsigned short* __restrict__ Q,   // prescaled by 0.125
        const unsigned short* __restrict__ K,
        const unsigned short* __restrict__ Vt,
        float* __restrict__ out) {
    __shared__ unsigned short KS[64][64];        // [j][d], swizzled
    __shared__ unsigned short VS[2][128][64];    // [buf][n][j], swizzled, dbuf
    __shared__ unsigned short PS[128][64];       // [q][j], swizzled
    __shared__ float lS[128];

    int t = threadIdx.x;
    int w = t >> 6, lane = t & 63;
    int l16 = lane & 15, hi = lane >> 4;
    int b = blockIdx.z;
    int dm0 = blockIdx.x * 128;
    int wn = w * 32;                             // wave's n-slice for PV

    // K reg-staging geometry (2 chunks/thread)
    int krow = t >> 3, kc = t & 7;               // rows 0..31 (+32 for rep 1)
    // V gload geometry (4 calls/thread): lds elems = rep*2048 + w*512 + lane*8
    int voff = w * 512 + lane * 8;
    int vrow = w * 8 + (lane >> 3);              // + rep*32
    int vcol = ((lane & 7) ^ (vrow & 7)) * 8;    // inverse-swizzled source chunk

    const unsigned short* Kb = K  + (size_t)b * S * DK;
    const unsigned short* Vb = Vt + ((size_t)b * DM + dm0) * S;

    #pragma unroll 1
    for (int half = 0; half < 2; ++half) {
        int qidx = half ? (15 - (int)blockIdx.y) : (int)blockIdx.y;
        int q0 = qidx * 128;
        int NJ = q0 + 128;
        int qw = q0 + w * 32;

        // Q B-fragments (cols = q), persistent: [qh][ks]
        s8v qf[2][2];
        #pragma unroll
        for (int qh = 0; qh < 2; ++qh)
            #pragma unroll
            for (int ks = 0; ks < 2; ++ks)
                qf[qh][ks] = ld8(Q + ((size_t)b * S + qw + qh * 16 + l16) * DK
                                   + ks * 32 + hi * 8);

        float lacc[2] = {0.f, 0.f};
        f4v acc[8][2] = {};

        // prologue: stage j0 = 0
        {
            s8v kr0 = ld8(Kb + (size_t)krow * DK + kc * 8);
            s8v kr1 = ld8(Kb + (size_t)(krow + 32) * DK + kc * 8);
            #pragma unroll
            for (int rep = 0; rep < 4; ++rep)
                gload16(Vb + (size_t)(rep * 32 + vrow) * S + vcol,
                        &VS[0][0][0] + rep * 2048 + voff);
            *(s8v*)&KS[krow][(kc ^ (krow & 7)) * 8] = kr0;
            *(s8v*)&KS[krow + 32][(kc ^ (krow & 7)) * 8] = kr1;
        }
        __syncthreads();

        int cur = 0;
        for (int j0 = 0; j0 < NJ; j0 += 64) {
            int jn = j0 + 64;
            bool pf = jn < NJ;
            s8v kp0, kp1;
            if (pf) {
                kp0 = ld8(Kb + (size_t)(jn + krow) * DK + kc * 8);
                kp1 = ld8(Kb + (size_t)(jn + krow + 32) * DK + kc * 8);
                #pragma unroll
                for (int rep = 0; rep < 4; ++rep)
                    gload16(Vb + (size_t)(rep * 32 + vrow) * S + jn + vcol,
                            &VS[cur ^ 1][0][0] + rep * 2048 + voff);
            }
            // QK^T transposed (Sc^T = K.Q^T), per-lane row = q; m=0 fixed
            #pragma unroll
            for (int jt = 0; jt < 4; ++jt) {
                int jrow = jt * 16 + l16;
                s8v ka0 = *(const s8v*)&KS[jrow][((0 + hi) ^ (jrow & 7)) * 8];
                s8v ka1 = *(const s8v*)&KS[jrow][((4 + hi) ^ (jrow & 7)) * 8];
                #pragma unroll
                for (int qh = 0; qh < 2; ++qh) {
                    f4v d = {0.f, 0.f, 0.f, 0.f};
                    d = mf16(ka0, qf[qh][0], d);
                    d = mf16(ka1, qf[qh][1], d);
                    int qg = qw + qh * 16 + l16;
                    int jbase = j0 + jt * 16 + hi * 4;
                    float p0 = (jbase + 0 <= qg) ? __expf(d[0]) : 0.f;
                    float p1 = (jbase + 1 <= qg) ? __expf(d[1]) : 0.f;
                    float p2 = (jbase + 2 <= qg) ? __expf(d[2]) : 0.f;
                    float p3 = (jbase + 3 <= qg) ? __expf(d[3]) : 0.f;
                    lacc[qh] += (p0 + p1) + (p2 + p3);
                    us4 pk;
                    pk.x = f2bf(p0); pk.y = f2bf(p1); pk.z = f2bf(p2); pk.w = f2bf(p3);
                    int prow = w * 32 + qh * 16 + l16;
                    int pc = jt * 2 + (hi >> 1);
                    *(us4*)&PS[prow][((pc ^ (prow & 7)) * 8) + (hi & 1) * 4] = pk;
                }
            }
            bar_lgkm();   // PS visible, KS reads done; V gloads remain in flight
            if (pf) {     // refill KS during PV (no one reads KS until next iter)
                *(s8v*)&KS[krow][(kc ^ (krow & 7)) * 8] = kp0;
                *(s8v*)&KS[krow + 32][(kc ^ (krow & 7)) * 8] = kp1;
            }
            // PV: O[128q x 32n(wave slice)] += P(128x64) . V(64j x 128n slice)
            __builtin_amdgcn_s_setprio(1);
            #pragma unroll
            for (int js = 0; js < 2; ++js) {
                s8v pa[8];
                #pragma unroll
                for (int qt = 0; qt < 8; ++qt) {
                    int qr = qt * 16 + l16;
                    pa[qt] = *(const s8v*)&PS[qr][((js * 4 + hi) ^ (qr & 7)) * 8];
                }
                #pragma unroll
                for (int nt = 0; nt < 2; ++nt) {
                    int nr = wn + nt * 16 + l16;
                    s8v vb = *(const s8v*)&VS[cur][nr][((js * 4 + hi) ^ (nr & 7)) * 8];
                    #pragma unroll
                    for (int qt = 0; qt < 8; ++qt)
                        acc[qt][nt] = mf16(pa[qt], vb, acc[qt][nt]);
                }
            }
            __builtin_amdgcn_s_setprio(0);
            __syncthreads();   // full drain: VS[cur^1] + KS ready for next iter
            cur ^= 1;
        }

        // denominators: lanes (l16,qh) share q across hi -> reduce over hi
        #pragma unroll
        for (int qh = 0; qh < 2; ++qh) {
            float lt = lacc[qh];
            lt += __shfl_xor(lt, 16);
            lt += __shfl_xor(lt, 32);
            if (hi == 0) lS[w * 32 + qh * 16 + l16] = lt;
        }
        __syncthreads();

        // epilogue: normalize + store fp32
        #pragma unroll
        for (int qt = 0; qt < 8; ++qt) {
            f4v lv = *(const f4v*)&lS[qt * 16 + hi * 4];
            f4v inv;
            inv[0] = 1.f / lv[0]; inv[1] = 1.f / lv[1];
            inv[2] = 1.f / lv[2]; inv[3] = 1.f / lv[3];
            size_t rbase = (size_t)b * S + q0 + qt * 16 + hi * 4;
            #pragma unroll
            for (int nt = 0; nt < 2; ++nt)
                #pragma unroll
                for (int r = 0; r < 4; ++r)
                    out[(rbase + r) * DM + dm0 + wn + nt * 16 + l16] =
                        acc[qt][nt][r] * inv[r];
        }
        __syncthreads();   // protect LDS before next half's prologue
    }
}

extern "C" void kernel_launch(void* const* d_in, const int* in_sizes, int n_in,
                              void* d_out, int out_size, void* d_ws, size_t ws_size,
                              hipStream_t stream) {
    const float* x  = (const float*)d_in[0];
    const float* Wq = (const float*)d_in[1];
    const float* bq = (const float*)d_in[2];
    const float* Wk = (const float*)d_in[3];
    const float* bk = (const float*)d_in[4];
    const float* Wv = (const float*)d_in[5];
    const float* bv = (const float*)d_in[6];
    float* out = (float*)d_out;

    unsigned short* xb   = (unsigned short*)d_ws;                // 16384x1024
    unsigned short* Wvt  = xb   + (size_t)M_ROWS * DM;           // 1024x1024
    unsigned short* Qb   = Wvt  + (size_t)DM * DM;               // 16384x64
    unsigned short* Kb   = Qb   + (size_t)M_ROWS * DK;           // 16384x64
    unsigned short* Vt   = Kb   + (size_t)M_ROWS * DK;           // 8x1024x2048
    unsigned short* Wqkt = Vt   + (size_t)B * DM * S;            // 128x1024

    cast_x<<<(size_t)M_ROWS * DM / 1024, 256, 0, stream>>>(x, xb);
    wv_t<<<dim3(32, 32), 256, 0, stream>>>(Wv, Wvt);
    wqk_t<<<dim3(4, 32), 256, 0, stream>>>(Wq, Wk, Wqkt);
    qk_mfma<<<M_ROWS / 64, 256, 0, stream>>>(xb, Wqkt, bq, bk, Qb, Kb);
    v_proj_mfma<<<dim3(DM / 128, M_ROWS / 128), 256, 0, stream>>>(xb, Wvt, bv, Vt);
    attn_mfma<<<dim3(DM / 128, 8, B), 256, 0, stream>>>(Qb, Kb, Vt, out);
}

// Round 9
// 280.376 us; speedup vs baseline: 1.3510x; 1.0383x over previous
//
#include <hip/hip_runtime.h>
#include <math.h>

#define B 8
#define S 2048
#define DM 1024
#define DK 64
#define M_ROWS (B*S)

typedef short s8v __attribute__((ext_vector_type(8)));     // 8 bf16 (4 VGPR)
typedef float f4v __attribute__((ext_vector_type(4)));     // 4 fp32
typedef unsigned short us4 __attribute__((ext_vector_type(4)));

__device__ __forceinline__ unsigned short f2bf(float f) {
    union { float f; unsigned u; } v; v.f = f;
    unsigned r = v.u + 0x7fffu + ((v.u >> 16) & 1u);   // RNE
    return (unsigned short)(r >> 16);
}
__device__ __forceinline__ s8v ld8(const unsigned short* p) {
    return *(const s8v*)p;
}
__device__ __forceinline__ f4v mf16(s8v a, s8v b, f4v c) {
    return __builtin_amdgcn_mfma_f32_16x16x32_bf16(a, b, c, 0, 0, 0);
}
// async global->LDS, 16B per lane.
__device__ __forceinline__ void gload16(const unsigned short* g, unsigned short* l) {
    __builtin_amdgcn_global_load_lds(
        (const __attribute__((address_space(1))) void*)g,
        (__attribute__((address_space(3))) void*)l, 16, 0, 0);
}

// ---------------- cast x (fp32 -> bf16) ----------------
__global__ __launch_bounds__(256) void cast_x(const float* __restrict__ x,
                                              unsigned short* __restrict__ xb) {
    size_t i = ((size_t)blockIdx.x * 256 + threadIdx.x) * 4;
    float4 v = *(const float4*)(x + i);
    us4 o; o.x = f2bf(v.x); o.y = f2bf(v.y); o.z = f2bf(v.z); o.w = f2bf(v.w);
    *(us4*)(xb + i) = o;
}

// ---------------- transpose + cast Wv -> Wvt[n][k] bf16 ----------------
__global__ __launch_bounds__(256) void wv_t(const float* __restrict__ Wv,
                                            unsigned short* __restrict__ Wvt) {
    __shared__ float T[32][33];
    int t = threadIdx.x;
    int k0 = blockIdx.y * 32, n0 = blockIdx.x * 32;
    int r = t >> 3, c = (t & 7) * 4;
    float4 v = *(const float4*)(Wv + (size_t)(k0 + r) * DM + n0 + c);
    T[r][c + 0] = v.x; T[r][c + 1] = v.y; T[r][c + 2] = v.z; T[r][c + 3] = v.w;
    __syncthreads();
    us4 o;
    o.x = f2bf(T[c + 0][r]); o.y = f2bf(T[c + 1][r]);
    o.z = f2bf(T[c + 2][r]); o.w = f2bf(T[c + 3][r]);
    *(us4*)(Wvt + (size_t)(n0 + r) * DM + k0 + c) = o;
}

// ---------------- transpose + cast Wq|Wk -> Wqkt[128][1024] bf16 ----------
__global__ __launch_bounds__(256) void wqk_t(const float* __restrict__ Wq,
                                             const float* __restrict__ Wk,
                                             unsigned short* __restrict__ Wqkt) {
    __shared__ float T[32][33];
    int t = threadIdx.x;
    int k0 = blockIdx.y * 32, n0 = blockIdx.x * 32;
    const float* src = (n0 < 64) ? Wq : Wk;
    int nc = (n0 < 64) ? n0 : (n0 - 64);
    int r = t >> 3, c = (t & 7) * 4;
    float4 v = *(const float4*)(src + (size_t)(k0 + r) * DK + nc + c);
    T[r][c + 0] = v.x; T[r][c + 1] = v.y; T[r][c + 2] = v.z; T[r][c + 3] = v.w;
    __syncthreads();
    us4 o;
    o.x = f2bf(T[c + 0][r]); o.y = f2bf(T[c + 1][r]);
    o.z = f2bf(T[c + 2][r]); o.w = f2bf(T[c + 3][r]);
    *(us4*)(Wqkt + (size_t)(n0 + r) * DM + k0 + c) = o;
}

// ---------------- Q/K projection: m97-style, global_load_lds, BK=64 -------
__global__ __launch_bounds__(256) void qk_mfma(
        const unsigned short* __restrict__ xb,
        const unsigned short* __restrict__ Wqkt,
        const float* __restrict__ bq, const float* __restrict__ bk,
        unsigned short* __restrict__ Q, unsigned short* __restrict__ Ko) {
    __shared__ unsigned short XS[64 * 64];
    __shared__ unsigned short WS[128 * 64];
    int t = threadIdx.x;
    int w = t >> 6, lane = t & 63, l16 = lane & 15, quad = lane >> 4;
    int m0 = blockIdx.x * 64;
    int wm = (w >> 1) * 32, wn = (w & 1) * 64;
    f4v acc[2][4] = {};
    int srow = w * 8 + (lane >> 3);
    int scol = ((lane & 7) ^ (srow & 7)) * 8;
    int soff = w * 512 + lane * 8;
    for (int k0 = 0; k0 < DM; k0 += 64) {
        __syncthreads();
        #pragma unroll
        for (int i = 0; i < 2; ++i)
            gload16(xb + (size_t)(m0 + i * 32 + srow) * DM + k0 + scol,
                    XS + i * 2048 + soff);
        #pragma unroll
        for (int i = 0; i < 4; ++i)
            gload16(Wqkt + (size_t)(i * 32 + srow) * DM + k0 + scol,
                    WS + i * 2048 + soff);
        __syncthreads();
        #pragma unroll
        for (int ks = 0; ks < 2; ++ks) {
            s8v af[2], bf[4];
            #pragma unroll
            for (int i = 0; i < 2; ++i) {
                int r = wm + i * 16 + l16;
                af[i] = *(const s8v*)&XS[r * 64 + ((ks * 4 + quad) ^ (r & 7)) * 8];
            }
            #pragma unroll
            for (int j = 0; j < 4; ++j) {
                int r = wn + j * 16 + l16;
                bf[j] = *(const s8v*)&WS[r * 64 + ((ks * 4 + quad) ^ (r & 7)) * 8];
            }
            #pragma unroll
            for (int i = 0; i < 2; ++i)
                #pragma unroll
                for (int j = 0; j < 4; ++j)
                    acc[i][j] = mf16(af[i], bf[j], acc[i][j]);
        }
    }
    #pragma unroll
    for (int j = 0; j < 4; ++j) {
        int n = wn + j * 16 + l16;
        float bias = (n < 64) ? bq[n] : bk[n - 64];
        float scale = (n < 64) ? 0.125f : 1.0f;
        unsigned short* dst = (n < 64) ? Q : Ko;
        int nn = n & 63;
        #pragma unroll
        for (int i = 0; i < 2; ++i)
            #pragma unroll
            for (int rr = 0; rr < 4; ++rr) {
                int m = m0 + wm + i * 16 + quad * 4 + rr;
                dst[(size_t)m * DK + nn] = f2bf((acc[i][j][rr] + bias) * scale);
            }
    }
}

// ---------------- V projection: m97-style, global_load_lds, BK=64 ---------
__global__ __launch_bounds__(256) void v_proj_mfma(
        const unsigned short* __restrict__ xb,
        const unsigned short* __restrict__ Wvt,
        const float* __restrict__ bv,
        unsigned short* __restrict__ Vt) {
    __shared__ unsigned short XS[128 * 64];
    __shared__ unsigned short WS[128 * 64];
    int t = threadIdx.x;
    int w = t >> 6, lane = t & 63, l16 = lane & 15, quad = lane >> 4;
    int m0 = blockIdx.y * 128, n0 = blockIdx.x * 128;
    int wm = (w >> 1) * 64, wn = (w & 1) * 64;
    f4v acc[4][4] = {};
    int srow = w * 8 + (lane >> 3);
    int scol = ((lane & 7) ^ (srow & 7)) * 8;
    int soff = w * 512 + lane * 8;
    for (int k0 = 0; k0 < DM; k0 += 64) {
        __syncthreads();
        #pragma unroll
        for (int i = 0; i < 4; ++i) {
            gload16(xb  + (size_t)(m0 + i * 32 + srow) * DM + k0 + scol,
                    XS + i * 2048 + soff);
            gload16(Wvt + (size_t)(n0 + i * 32 + srow) * DM + k0 + scol,
                    WS + i * 2048 + soff);
        }
        __syncthreads();
        #pragma unroll
        for (int ks = 0; ks < 2; ++ks) {
            s8v af[4], bf[4];
            #pragma unroll
            for (int i = 0; i < 4; ++i) {
                int r = wm + i * 16 + l16;
                af[i] = *(const s8v*)&XS[r * 64 + ((ks * 4 + quad) ^ (r & 7)) * 8];
            }
            #pragma unroll
            for (int j = 0; j < 4; ++j) {
                int r = wn + j * 16 + l16;
                bf[j] = *(const s8v*)&WS[r * 64 + ((ks * 4 + quad) ^ (r & 7)) * 8];
            }
            #pragma unroll
            for (int i = 0; i < 4; ++i)
                #pragma unroll
                for (int j = 0; j < 4; ++j)
                    acc[i][j] = mf16(af[i], bf[j], acc[i][j]);
        }
    }
    int bb = m0 >> 11;
    #pragma unroll
    for (int j = 0; j < 4; ++j) {
        int n = n0 + wn + j * 16 + l16;
        float bias = bv[n];
        #pragma unroll
        for (int i = 0; i < 4; ++i) {
            int m = m0 + wm + i * 16 + quad * 4;
            int s = m & (S - 1);
            us4 o;
            o.x = f2bf(acc[i][j][0] + bias); o.y = f2bf(acc[i][j][1] + bias);
            o.z = f2bf(acc[i][j][2] + bias); o.w = f2bf(acc[i][j][3] + bias);
            *(us4*)(Vt + ((size_t)bb * DM + n) * S + s) = o;
        }
    }
}

// ---------------- MFMA flash attention v4.1 ----------------
// v4 LDS-traffic redesign with CONSERVATIVE sync (race fix):
// - 512 threads (8 waves), dm-slice 256, 1 block/CU (82KB LDS).
// - K fragments loaded straight from global (L2-hot, XCD-pinned) -> no KS.
// - QK: 8-way q-split (16 q-rows/wave); PV: 2q x 4n split (64x64/wave).
// - V double-buffered via global_load_lds (inverse-swizzled source).
// - P packed with v_cvt_pk_bf16_f32.
// - BOTH in-loop barriers are full __syncthreads() (vmcnt+lgkm drain) --
//   no vmem deliberately in flight across any barrier.
// - PS/lS declared first -> cross-wave P handoff below the 64KB LDS line.
__global__ __launch_bounds__(512, 2) void attn_mfma(
        const unsigned short* __restrict__ Q,   // prescaled by 0.125
        const unsigned short* __restrict__ K,
        const unsigned short* __restrict__ Vt,
        float* __restrict__ out) {
    __shared__ unsigned short PS[128][64];       // [q][j], swizzled (low LDS)
    __shared__ float lS[128];
    __shared__ unsigned short VS[2][256][64];    // [buf][n][j], swizzled, dbuf

    int t = threadIdx.x;
    int w = t >> 6, lane = t & 63;
    int l16 = lane & 15, hi = lane >> 4;
    int bid = blockIdx.x;
    int b  = bid & 7;                            // dispatch%8 -> XCD = batch
    int bx = (bid >> 3) & 3;
    int by = bid >> 5;
    int dm0 = bx * 256;
    int wn = (w & 3) * 64;                       // PV n-slice (4 groups)
    int qg = (w >> 2) * 64;                      // PV q-slice (2 groups)

    // V gload geometry: thread t covers chunk (t&7) of LDS row rep*64+(t>>3)
    int vrow = t >> 3;
    int voff = t * 8;                            // LDS elems; + rep*4096
    int gcol = ((t & 7) ^ ((t >> 3) & 7)) * 8;   // inverse-swizzled source chunk

    const unsigned short* Kb = K  + (size_t)b * S * DK;
    const unsigned short* Vb = Vt + ((size_t)b * DM + dm0) * S;
    const unsigned short* kbase = Kb + (size_t)l16 * DK + hi * 8;

    #pragma unroll 1
    for (int half = 0; half < 2; ++half) {
        int qidx = half ? (15 - by) : by;
        int q0 = qidx * 128;
        int NJ = q0 + 128;
        int qw = q0 + w * 16;                    // QK q-slice (16 rows/wave)

        // Q B-fragments (cols = q), persistent
        s8v qf[2];
        #pragma unroll
        for (int ks = 0; ks < 2; ++ks)
            qf[ks] = ld8(Q + ((size_t)b * S + qw + l16) * DK + ks * 32 + hi * 8);

        float lacc = 0.f;
        f4v acc[4][4] = {};                      // [qt][nt], 64q x 64n per wave

        // prologue: stage j0 = 0 (V -> LDS async, K -> regs)
        s8v ka[8];                               // [jt*2+ks]
        #pragma unroll
        for (int rep = 0; rep < 4; ++rep)
            gload16(Vb + (size_t)(rep * 64 + vrow) * S + gcol,
                    &VS[0][0][0] + rep * 4096 + voff);
        #pragma unroll
        for (int jt = 0; jt < 4; ++jt)
            #pragma unroll
            for (int ks = 0; ks < 2; ++ks)
                ka[jt * 2 + ks] = ld8(kbase + (size_t)(jt * 16) * DK + ks * 32);
        __syncthreads();

        int cur = 0;
        for (int j0 = 0; j0 < NJ; j0 += 64) {
            int jn = j0 + 64;
            bool pf = jn < NJ;
            if (pf) {
                #pragma unroll
                for (int rep = 0; rep < 4; ++rep)
                    gload16(Vb + (size_t)(rep * 64 + vrow) * S + jn + gcol,
                            &VS[cur ^ 1][0][0] + rep * 4096 + voff);
            }
            // QK^T transposed (Sc^T = K.Q^T): 64j x 16q per wave; m=0 fixed
            #pragma unroll
            for (int jt = 0; jt < 4; ++jt) {
                f4v d = {0.f, 0.f, 0.f, 0.f};
                d = mf16(ka[jt * 2 + 0], qf[0], d);
                d = mf16(ka[jt * 2 + 1], qf[1], d);
                int qglob = qw + l16;
                int jbase = j0 + jt * 16 + hi * 4;
                float p0 = (jbase + 0 <= qglob) ? __expf(d[0]) : 0.f;
                float p1 = (jbase + 1 <= qglob) ? __expf(d[1]) : 0.f;
                float p2 = (jbase + 2 <= qglob) ? __expf(d[2]) : 0.f;
                float p3 = (jbase + 3 <= qglob) ? __expf(d[3]) : 0.f;
                lacc += (p0 + p1) + (p2 + p3);
                unsigned r0, r1;
                asm("v_cvt_pk_bf16_f32 %0, %1, %2" : "=v"(r0) : "v"(p0), "v"(p1));
                asm("v_cvt_pk_bf16_f32 %0, %1, %2" : "=v"(r1) : "v"(p2), "v"(p3));
                int prow = w * 16 + l16;
                int pc = jt * 2 + (hi >> 1);
                uint2 pk2; pk2.x = r0; pk2.y = r1;
                *(uint2*)&PS[prow][((pc ^ (prow & 7)) * 8) + (hi & 1) * 4] = pk2;
            }
            // prefetch next K tile into regs
            if (pf) {
                #pragma unroll
                for (int jt = 0; jt < 4; ++jt)
                    #pragma unroll
                    for (int ks = 0; ks < 2; ++ks)
                        ka[jt * 2 + ks] =
                            ld8(kbase + (size_t)(jn + jt * 16) * DK + ks * 32);
            }
            __syncthreads();   // full drain: PS visible, V(this iter) landed
            // PV: O[64q x 64n per wave] += P(64x64 slice) . V(64j x 64n slice)
            __builtin_amdgcn_s_setprio(1);
            #pragma unroll
            for (int js = 0; js < 2; ++js) {
                s8v pa[4];
                #pragma unroll
                for (int qt = 0; qt < 4; ++qt) {
                    int qr = qg + qt * 16 + l16;
                    pa[qt] = *(const s8v*)&PS[qr][((js * 4 + hi) ^ (qr & 7)) * 8];
                }
                #pragma unroll
                for (int nt = 0; nt < 4; ++nt) {
                    int nr = wn + nt * 16 + l16;
                    s8v vb = *(const s8v*)&VS[cur][nr][((js * 4 + hi) ^ (nr & 7)) * 8];
                    #pragma unroll
                    for (int qt = 0; qt < 4; ++qt)
                        acc[qt][nt] = mf16(pa[qt], vb, acc[qt][nt]);
                }
            }
            __builtin_amdgcn_s_setprio(0);
            __syncthreads();   // PV reads done before next iter's writes
            cur ^= 1;
        }

        // denominators: lanes (l16) share q across hi -> reduce over hi
        {
            float lt = lacc;
            lt += __shfl_xor(lt, 16);
            lt += __shfl_xor(lt, 32);
            if (hi == 0) lS[w * 16 + l16] = lt;
        }
        __syncthreads();

        // epilogue: normalize + store fp32
        #pragma unroll
        for (int qt = 0; qt < 4; ++qt) {
            f4v lv = *(const f4v*)&lS[qg + qt * 16 + hi * 4];
            f4v inv;
            inv[0] = 1.f / lv[0]; inv[1] = 1.f / lv[1];
            inv[2] = 1.f / lv[2]; inv[3] = 1.f / lv[3];
            size_t rbase = (size_t)b * S + q0 + qg + qt * 16 + hi * 4;
            #pragma unroll
            for (int nt = 0; nt < 4; ++nt)
                #pragma unroll
                for (int r = 0; r < 4; ++r)
                    out[(rbase + r) * DM + dm0 + wn + nt * 16 + l16] =
                        acc[qt][nt][r] * inv[r];
        }
        __syncthreads();   // protect LDS before next half's prologue
    }
}

extern "C" void kernel_launch(void* const* d_in, const int* in_sizes, int n_in,
                              void* d_out, int out_size, void* d_ws, size_t ws_size,
                              hipStream_t stream) {
    const float* x  = (const float*)d_in[0];
    const float* Wq = (const float*)d_in[1];
    const float* bq = (const float*)d_in[2];
    const float* Wk = (const float*)d_in[3];
    const float* bk = (const float*)d_in[4];
    const float* Wv = (const float*)d_in[5];
    const float* bv = (const float*)d_in[6];
    float* out = (float*)d_out;

    unsigned short* xb   = (unsigned short*)d_ws;                // 16384x1024
    unsigned short* Wvt  = xb   + (size_t)M_ROWS * DM;           // 1024x1024
    unsigned short* Qb   = Wvt  + (size_t)DM * DM;               // 16384x64
    unsigned short* Kb   = Qb   + (size_t)M_ROWS * DK;           // 16384x64
    unsigned short* Vt   = Kb   + (size_t)M_ROWS * DK;           // 8x1024x2048
    unsigned short* Wqkt = Vt   + (size_t)B * DM * S;            // 128x1024

    cast_x<<<(size_t)M_ROWS * DM / 1024, 256, 0, stream>>>(x, xb);
    wv_t<<<dim3(32, 32), 256, 0, stream>>>(Wv, Wvt);
    wqk_t<<<dim3(4, 32), 256, 0, stream>>>(Wq, Wk, Wqkt);
    qk_mfma<<<M_ROWS / 64, 256, 0, stream>>>(xb, Wqkt, bq, bk, Qb, Kb);
    v_proj_mfma<<<dim3(DM / 128, M_ROWS / 128), 256, 0, stream>>>(xb, Wvt, bv, Vt);
    attn_mfma<<<dim3(256), 512, 0, stream>>>(Qb, Kb, Vt, out);
}